// Round 13
// baseline (133.999 us; speedup 1.0000x reference)
//
#include <hip/hip_runtime.h>
#include <hip/hip_bf16.h>
#include <math.h>

#define F_IN   256
#define F_OUT  128
#define ALPHA  0.2f
#define TM     64       // GEMM row tile

typedef __attribute__((ext_vector_type(8))) short s16x8;
typedef __attribute__((ext_vector_type(4))) float f32x4;

__device__ __forceinline__ ushort f2bf(float f) {
  __hip_bfloat16 h = __float2bfloat16(f);
  return *reinterpret_cast<ushort*>(&h);
}
__device__ __forceinline__ uint pk2bf(float lo, float hi) {
  return (uint)f2bf(lo) | ((uint)f2bf(hi) << 16);
}
__device__ __forceinline__ float bflo(uint u) { return __uint_as_float(u << 16); }
__device__ __forceinline__ float bfhi(uint u) { return __uint_as_float(u & 0xffff0000u); }

// ---------------------------------------------------------------------------
// Prep: blocks [0,ZB): zero deg (int4); [ZB,ZB+16): pack Wf; ZB+16: pack Wfs.
// ---------------------------------------------------------------------------
__global__ __launch_bounds__(256) void prep_kernel(
    const float* __restrict__ W, const float* __restrict__ avec,
    ushort* __restrict__ Wf, ushort* __restrict__ Wfs,
    int4* __restrict__ deg4, int n4, int ZB) {
  int b = blockIdx.x;
  if (b < ZB) {
    int i = b * 256 + threadIdx.x;
    if (i < n4) deg4[i] = make_int4(0, 0, 0, 0);
  } else if (b < ZB + 16) {
    int idx = (b - ZB) * 256 + threadIdx.x;   // 4096 fragments-of-8
    int kb = idx >> 7, c = idx & 127;
    union { s16x8 v; ushort u[8]; } t;
#pragma unroll
    for (int j = 0; j < 8; ++j) t.u[j] = f2bf(W[(kb * 8 + j) * F_OUT + c]);
    *(s16x8*)&Wf[(size_t)idx * 8] = t.v;
  } else {
    int k = threadIdx.x;   // 0..255 = K row of W
    float s1 = 0.f, s2 = 0.f;
    for (int c = 0; c < F_OUT; ++c) {
      float wv = W[k * F_OUT + c];
      s1 += wv * avec[c];
      s2 += wv * avec[F_OUT + c];
    }
    int kb = k >> 3, j8 = k & 7;
    ushort b1 = f2bf(s1), b2 = f2bf(s2);
#pragma unroll
    for (int cc = 0; cc < 16; ++cc) {
      ushort v = (cc == 0) ? b1 : (cc == 1) ? b2 : (ushort)0;
      Wfs[((size_t)kb * 16 + cc) * 8 + j8] = v;
    }
  }
}

// ---------------------------------------------------------------------------
// GEMM, barrier-free / LDS-free: Hb32[M][64] u32 = packed bf16 cols (l,l+64)
// of H = bf16(X) @ W. 64-row tile, 4 waves; wave w owns col-frags j=w, j=w+4.
// A-frags loaded DIRECTLY from global per (rf,ks): lane l reads 8 contiguous
// fp32 at X[row0+rf*16+(l&15)][(ks*4+lg)*8], converts in-register (same
// values as the old LDS-staged path -> bit-identical output). The 4 waves
// touch the same 2KB window per (rf,ks) in near-lockstep -> L1 absorbs the
// redundancy. B-frags per-ks from L2-hot Wf. No __syncthreads anywhere:
// removes the stage->drain->barrier critical path (was ~72% of the old
// kernel per the 2-phase stall model). s_src/s_dst via 9th B-frag on wave 0.
// ---------------------------------------------------------------------------
__global__ __launch_bounds__(256) void gemm_mfma_kernel(
    const float* __restrict__ X, const ushort* __restrict__ Wf,
    const ushort* __restrict__ Wfs,
    uint* __restrict__ Hb32, float* __restrict__ s_src, float* __restrict__ s_dst,
    int M) {
  const int tid = threadIdx.x;
  const int l = tid & 63;
  const int w = tid >> 6;
  const int lc = l & 15;
  const int lg = l >> 4;
  const int row0 = blockIdx.x * TM;

  // Per-lane row base pointers for the 4 row-frags (row-clamped; OOB rows
  // compute garbage that is never stored).
  const float* xp[4];
#pragma unroll
  for (int rf = 0; rf < 4; ++rf) {
    int gr = row0 + rf * 16 + lc;
    gr = (gr < M) ? gr : (M - 1);
    xp[rf] = X + (size_t)gr * F_IN + lg * 8;
  }

  f32x4 acc0[4] = {}, acc1[4] = {}, accS[4] = {};
#pragma unroll
  for (int ks = 0; ks < 8; ++ks) {
    // A loads: 8 x 16B issued together (independent), k-offset = ks*32 floats
    f32x4 ra[4][2];
#pragma unroll
    for (int rf = 0; rf < 4; ++rf) {
      const f32x4* p = (const f32x4*)(xp[rf] + ks * 32);
      ra[rf][0] = p[0];
      ra[rf][1] = p[1];
    }
    // B-frags for this ks (L2-hot: every block reads the same 64KB Wf)
    int kb = ks * 4 + lg;
    s16x8 b0 = *(const s16x8*)&Wf[((size_t)kb * F_OUT + w * 16 + lc) * 8];
    s16x8 b1 = *(const s16x8*)&Wf[((size_t)kb * F_OUT + 64 + w * 16 + lc) * 8];
    s16x8 bS;
    if (w == 0) bS = *(const s16x8*)&Wfs[((size_t)kb * 16 + lc) * 8];

#pragma unroll
    for (int rf = 0; rf < 4; ++rf) {
      union { s16x8 v; ushort u[8]; } t;
      t.u[0] = f2bf(ra[rf][0][0]); t.u[1] = f2bf(ra[rf][0][1]);
      t.u[2] = f2bf(ra[rf][0][2]); t.u[3] = f2bf(ra[rf][0][3]);
      t.u[4] = f2bf(ra[rf][1][0]); t.u[5] = f2bf(ra[rf][1][1]);
      t.u[6] = f2bf(ra[rf][1][2]); t.u[7] = f2bf(ra[rf][1][3]);
      acc0[rf] = __builtin_amdgcn_mfma_f32_16x16x32_bf16(t.v, b0, acc0[rf], 0, 0, 0);
      acc1[rf] = __builtin_amdgcn_mfma_f32_16x16x32_bf16(t.v, b1, acc1[rf], 0, 0, 0);
      if (w == 0)
        accS[rf] = __builtin_amdgcn_mfma_f32_16x16x32_bf16(t.v, bS, accS[rf], 0, 0, 0);
    }
  }

  // Hb store: u32 slot s = w*16+lc holds cols (s, s+64) as (lo, hi) bf16.
#pragma unroll
  for (int rf = 0; rf < 4; ++rf) {
#pragma unroll
    for (int q = 0; q < 4; ++q) {
      int rg = row0 + rf * 16 + lg * 4 + q;
      if (rg < M)
        Hb32[(size_t)rg * 64 + w * 16 + lc] = pk2bf(acc0[rf][q], acc1[rf][q]);
    }
  }

  // s_src (lc==0) / s_dst (lc==1) straight from accS.
  if (w == 0 && lc < 2) {
    float* sout = (lc == 0) ? s_src : s_dst;
#pragma unroll
    for (int rf = 0; rf < 4; ++rf) {
#pragma unroll
      for (int q = 0; q < 4; ++q) {
        int rg = row0 + rf * 16 + lg * 4 + q;
        if (rg < M) sout[rg] = accS[rf][q];
      }
    }
  }
}

// ---------------------------------------------------------------------------
// Hist standalone (8 VGPR, full occupancy for atomic latency hiding):
// deg histogram AND per-edge rank (the atomicAdd return), 4 edges/thread.
// ---------------------------------------------------------------------------
__global__ __launch_bounds__(256) void hist_rank_kernel(
    const int* __restrict__ src, int* __restrict__ deg,
    int* __restrict__ rank, int E) {
  int e0 = (blockIdx.x * 256 + threadIdx.x) * 4;
  if (e0 + 4 <= E) {
    int4 s4 = *(const int4*)(src + e0);
    int4 r4;
    r4.x = atomicAdd(&deg[s4.x], 1);
    r4.y = atomicAdd(&deg[s4.y], 1);
    r4.z = atomicAdd(&deg[s4.z], 1);
    r4.w = atomicAdd(&deg[s4.w], 1);
    *(int4*)(rank + e0) = r4;
  } else {
    for (int e = e0; e < E; ++e) rank[e] = atomicAdd(&deg[src[e]], 1);
  }
}

// ---------------------------------------------------------------------------
// Per-256-chunk sums of deg (input to the fused scan).
// ---------------------------------------------------------------------------
__global__ void block_sums_kernel(const int* __restrict__ deg, int* __restrict__ bs, int N) {
  int i = blockIdx.x * 256 + threadIdx.x;
  int v = (i < N) ? deg[i] : 0;
  int lane = threadIdx.x & 63, w = threadIdx.x >> 6;
#pragma unroll
  for (int d = 32; d >= 1; d >>= 1) v += __shfl_down(v, d);
  __shared__ int wsum[4];
  if (lane == 0) wsum[w] = v;
  __syncthreads();
  if (threadIdx.x == 0) bs[blockIdx.x] = wsum[0] + wsum[1] + wsum[2] + wsum[3];
}

// ---------------------------------------------------------------------------
// Fused scan: every block redundantly exclusive-scans bs[0..NS) (NS<=256)
// to get its offset, then scans its 256 deg values.
// ---------------------------------------------------------------------------
__global__ void scan_deg_kernel(const int* __restrict__ deg, const int* __restrict__ bs,
                                int* __restrict__ rowptr, int N, int E, int NS) {
  __shared__ int sc[256];
  __shared__ int wsumA[4], wsumB[4];
  int tid = threadIdx.x;
  int lane = tid & 63, w = tid >> 6;

  int bv = (tid < NS) ? bs[tid] : 0;
  int ibv = bv;
#pragma unroll
  for (int d = 1; d < 64; d <<= 1) {
    int t = __shfl_up(ibv, d);
    if (lane >= d) ibv += t;
  }
  if (lane == 63) wsumA[w] = ibv;
  __syncthreads();
  int boff = 0;
  for (int x = 0; x < w; ++x) boff += wsumA[x];
  sc[tid] = boff + ibv - bv;          // exclusive prefix of bs

  int i = blockIdx.x * 256 + tid;
  int v = (i < N) ? deg[i] : 0;
  int iv = v;
#pragma unroll
  for (int d = 1; d < 64; d <<= 1) {
    int t = __shfl_up(iv, d);
    if (lane >= d) iv += t;
  }
  if (lane == 63) wsumB[w] = iv;
  __syncthreads();                    // covers sc and wsumB
  int off = sc[blockIdx.x];
  for (int x = 0; x < w; ++x) off += wsumB[x];
  int excl = off + iv - v;
  if (i < N) rowptr[i] = excl;
  if (i == N - 1) rowptr[N] = E;
}

// ---------------------------------------------------------------------------
// Atomic-free scatter: colidx[rowptr[s] + rank[e]] = dst[e].
// ---------------------------------------------------------------------------
__global__ __launch_bounds__(256) void scatter_kernel(
    const int* __restrict__ src, const int* __restrict__ dst,
    const int* __restrict__ rank, const int* __restrict__ rowptr,
    int* __restrict__ colidx, int E) {
  int e0 = (blockIdx.x * 256 + threadIdx.x) * 4;
  if (e0 + 4 <= E) {
    int4 s4 = *(const int4*)(src + e0);
    int4 d4 = *(const int4*)(dst + e0);
    int4 r4 = *(const int4*)(rank + e0);
    colidx[rowptr[s4.x] + r4.x] = d4.x;
    colidx[rowptr[s4.y] + r4.y] = d4.y;
    colidx[rowptr[s4.z] + r4.z] = d4.z;
    colidx[rowptr[s4.w] + r4.w] = d4.w;
  } else {
    for (int e = e0; e < E; ++e) colidx[rowptr[src[e]] + rank[e]] = dst[e];
  }
}

// ---------------------------------------------------------------------------
// Aggregation: one wave per node (4/block). Lane-parallel softmax per
// <=64-edge chunk, then 4-edge-parallel gather: wave = 4 groups x 16 lanes,
// group g takes edge k+g, lane lc loads uint4 (16B). 8 edges/iter.
// Final shfl_xor(16,32) group-reduce. Slot s packs cols (s, s+64).
// ---------------------------------------------------------------------------
__global__ __launch_bounds__(256) void aggregate_kernel(
    const uint* __restrict__ H32, const float* __restrict__ s_src,
    const float* __restrict__ s_dst, const int* __restrict__ rowptr,
    const int* __restrict__ colidx, float* __restrict__ out, int M) {
  int node = blockIdx.x * 4 + (threadIdx.x >> 6);
  int l = threadIdx.x & 63;
  if (node >= M) return;
  const int g = l >> 4;       // edge group 0..3
  const int lc = l & 15;      // column lane within group
  int beg = rowptr[node], end = rowptr[node + 1];
  float ssrc = s_src[node];
  float m = -INFINITY, denom = 0.f;
  float acc[8] = {};

  for (int base = beg; base < end; base += 64) {
    int cnt = end - base; if (cnt > 64) cnt = 64;
    int jv = 0; float ev = -INFINITY;
    if (l < cnt) {
      jv = colidx[base + l];
      float e = ssrc + s_dst[jv];
      ev = (e > 0.f) ? e : ALPHA * e;
    }
    float cm = ev;
#pragma unroll
    for (int mask = 1; mask < 64; mask <<= 1) cm = fmaxf(cm, __shfl_xor(cm, mask));
    float mn = fmaxf(m, cm);
    float wv = (l < cnt) ? __expf(ev - mn) : 0.f;
    float sw = wv;
#pragma unroll
    for (int mask = 1; mask < 64; mask <<= 1) sw += __shfl_xor(sw, mask);
    float resc = __expf(m - mn);   // first chunk: exp(-inf) = 0
    denom = denom * resc + sw;
#pragma unroll
    for (int t = 0; t < 8; ++t) acc[t] *= resc;
    m = mn;

    for (int k = 0; k < cnt; k += 8) {
      int k0 = k + g, k1 = k + 4 + g;
      int j0 = __shfl(jv, k0);
      int j1 = (k1 < 64) ? __shfl(jv, k1) : 0;
      float w0 = __shfl(wv, k0);
      float w1 = (k1 < 64) ? __shfl(wv, k1) : 0.f;
      uint4 u0 = *(const uint4*)(H32 + ((size_t)(uint)j0 << 6) + lc * 4);
      uint4 u1 = *(const uint4*)(H32 + ((size_t)(uint)j1 << 6) + lc * 4);
      acc[0] += w0 * bflo(u0.x) + w1 * bflo(u1.x);
      acc[1] += w0 * bfhi(u0.x) + w1 * bfhi(u1.x);
      acc[2] += w0 * bflo(u0.y) + w1 * bflo(u1.y);
      acc[3] += w0 * bfhi(u0.y) + w1 * bfhi(u1.y);
      acc[4] += w0 * bflo(u0.z) + w1 * bflo(u1.z);
      acc[5] += w0 * bfhi(u0.z) + w1 * bfhi(u1.z);
      acc[6] += w0 * bflo(u0.w) + w1 * bflo(u1.w);
      acc[7] += w0 * bfhi(u0.w) + w1 * bfhi(u1.w);
    }
  }

#pragma unroll
  for (int t = 0; t < 8; ++t) {
    acc[t] += __shfl_xor(acc[t], 16);
    acc[t] += __shfl_xor(acc[t], 32);
  }
  float inv = (denom > 0.f) ? 1.f / denom : 0.f;
  if (g == 0) {
    float4 v;
    v.x = acc[0] * inv; v.y = acc[2] * inv; v.z = acc[4] * inv; v.w = acc[6] * inv;
    v.x = (v.x > 0.f) ? v.x : __expf(v.x) - 1.f;
    v.y = (v.y > 0.f) ? v.y : __expf(v.y) - 1.f;
    v.z = (v.z > 0.f) ? v.z : __expf(v.z) - 1.f;
    v.w = (v.w > 0.f) ? v.w : __expf(v.w) - 1.f;
    *(float4*)&out[(size_t)node * 128 + lc * 4] = v;
  } else if (g == 1) {
    float4 v;
    v.x = acc[1] * inv; v.y = acc[3] * inv; v.z = acc[5] * inv; v.w = acc[7] * inv;
    v.x = (v.x > 0.f) ? v.x : __expf(v.x) - 1.f;
    v.y = (v.y > 0.f) ? v.y : __expf(v.y) - 1.f;
    v.z = (v.z > 0.f) ? v.z : __expf(v.z) - 1.f;
    v.w = (v.w > 0.f) ? v.w : __expf(v.w) - 1.f;
    *(float4*)&out[(size_t)node * 128 + 64 + lc * 4] = v;
  }
}

// ---------------------------------------------------------------------------
extern "C" void kernel_launch(void* const* d_in, const int* in_sizes, int n_in,
                              void* d_out, int out_size, void* d_ws, size_t ws_size,
                              hipStream_t stream) {
  const float* x    = (const float*)d_in[0];
  const float* W    = (const float*)d_in[1];
  const float* avec = (const float*)d_in[2];
  const int*   edge = (const int*)d_in[3];

  const int M = in_sizes[0] / F_IN;   // 50000
  const int E = in_sizes[3] / 2;      // 800000
  const int* src = edge;
  const int* dst = edge + E;
  float* out = (float*)d_out;

  char* ws = (char*)d_ws;
  uint*   Hb32  = (uint*)ws;   ws += (size_t)M * 64 * sizeof(uint);
  ushort* Wf    = (ushort*)ws; ws += (size_t)32 * F_OUT * 8 * sizeof(ushort);
  ushort* Wfs   = (ushort*)ws; ws += (size_t)32 * 16 * 8 * sizeof(ushort);
  float* s_src  = (float*)ws;  ws += (size_t)M * sizeof(float);
  float* s_dst  = (float*)ws;  ws += (size_t)M * sizeof(float);
  int*   deg    = (int*)ws;    ws += (size_t)M * sizeof(int);
  int*   rowptr = (int*)ws;    ws += (size_t)(M + 1) * sizeof(int);
  int*   rank   = (int*)ws;    ws += (size_t)E * sizeof(int);
  int*   colidx = (int*)ws;    ws += (size_t)E * sizeof(int);
  int*   bsums  = (int*)ws;

  const int NS = (M + 255) / 256;                      // 196 (<= 256 required)
  const int n4 = M / 4;                                // deg zero (M % 4 == 0)
  const int ZB = (n4 + 255) / 256;                     // zero blocks
  const int E4 = (E + 1023) / 1024;                    // 4-edge/thread blocks
  const int G  = (M + TM - 1) / TM;                    // gemm blocks

  prep_kernel<<<ZB + 17, 256, 0, stream>>>(W, avec, Wf, Wfs, (int4*)deg, n4, ZB);
  hist_rank_kernel<<<E4, 256, 0, stream>>>(src, deg, rank, E);
  gemm_mfma_kernel<<<G, 256, 0, stream>>>(x, Wf, Wfs, Hb32, s_src, s_dst, M);
  block_sums_kernel<<<NS, 256, 0, stream>>>(deg, bsums, M);
  scan_deg_kernel<<<NS, 256, 0, stream>>>(deg, bsums, rowptr, M, E, NS);
  scatter_kernel<<<E4, 256, 0, stream>>>(src, dst, rank, rowptr, colidx, E);
  aggregate_kernel<<<(M + 3) / 4, 256, 0, stream>>>(Hb32, s_src, s_dst, rowptr, colidx, out, M);
}

// Round 14
// 117.845 us; speedup vs baseline: 1.1371x; 1.1371x over previous
//
#include <hip/hip_runtime.h>
#include <hip/hip_bf16.h>
#include <math.h>

#define F_IN   256
#define F_OUT  128
#define ALPHA  0.2f
#define TM     64       // GEMM row tile (4 waves x 16 rows)

typedef __attribute__((ext_vector_type(8))) short s16x8;
typedef __attribute__((ext_vector_type(4))) float f32x4;

__device__ __forceinline__ ushort f2bf(float f) {
  __hip_bfloat16 h = __float2bfloat16(f);
  return *reinterpret_cast<ushort*>(&h);
}
__device__ __forceinline__ uint pk2bf(float lo, float hi) {
  return (uint)f2bf(lo) | ((uint)f2bf(hi) << 16);
}
__device__ __forceinline__ float bflo(uint u) { return __uint_as_float(u << 16); }
__device__ __forceinline__ float bfhi(uint u) { return __uint_as_float(u & 0xffff0000u); }

// ---------------------------------------------------------------------------
// Prep: blocks [0,ZB): zero deg (int4); [ZB,ZB+16): pack Wf; ZB+16: pack Wfs.
// ---------------------------------------------------------------------------
__global__ __launch_bounds__(256) void prep_kernel(
    const float* __restrict__ W, const float* __restrict__ avec,
    ushort* __restrict__ Wf, ushort* __restrict__ Wfs,
    int4* __restrict__ deg4, int n4, int ZB) {
  int b = blockIdx.x;
  if (b < ZB) {
    int i = b * 256 + threadIdx.x;
    if (i < n4) deg4[i] = make_int4(0, 0, 0, 0);
  } else if (b < ZB + 16) {
    int idx = (b - ZB) * 256 + threadIdx.x;   // 4096 fragments-of-8
    int kb = idx >> 7, c = idx & 127;
    union { s16x8 v; ushort u[8]; } t;
#pragma unroll
    for (int j = 0; j < 8; ++j) t.u[j] = f2bf(W[(kb * 8 + j) * F_OUT + c]);
    *(s16x8*)&Wf[(size_t)idx * 8] = t.v;
  } else {
    int k = threadIdx.x;   // 0..255 = K row of W
    float s1 = 0.f, s2 = 0.f;
    for (int c = 0; c < F_OUT; ++c) {
      float wv = W[k * F_OUT + c];
      s1 += wv * avec[c];
      s2 += wv * avec[F_OUT + c];
    }
    int kb = k >> 3, j8 = k & 7;
    ushort b1 = f2bf(s1), b2 = f2bf(s2);
#pragma unroll
    for (int cc = 0; cc < 16; ++cc) {
      ushort v = (cc == 0) ? b1 : (cc == 1) ? b2 : (ushort)0;
      Wfs[((size_t)kb * 16 + cc) * 8 + j8] = v;
    }
  }
}

// ---------------------------------------------------------------------------
// GEMM, wave-autonomous (NO __syncthreads): each wave owns 16 rows x all 128
// cols and stages its own rows into its own 8KB LDS quarter. Producer ==
// consumer wave => same-wave LDS ordering (compiler lgkmcnt) suffices; the
// block-wide stage->vmcnt-drain->barrier critical path (~72% of the 2-phase
// kernel) is gone, while global loads stay fully coalesced (lanes 0-31 = one
// row's 1KB, lanes 32-63 = next row). r13's direct-global variant was
// UNcoalesced (16x128B segments/instr) -> 46us; this keeps both properties.
//
// Staging: iter i stages rows 2i,2i+1 of the wave's window: lane l (h=l>>5,
// kbs=l&31) loads X[row+2i+h][kbs*8..+8] (32B), converts to 8 bf16, writes
// 16B LDS at kbs*256 + ((2i+h) ^ (kbs&7))*16  [XOR swizzle both sides].
// A-frag read per ks: lane l reads kb=ks*4+lg, byte kb*256+((lc)^(kb&7))*16
// -> conflict-free b128. B-frags per ks from L2-hot Wf (all blocks share).
// C/D: col=l&15, row=(l>>4)*4+q. Hb32 slot s=j*16+lc packs cols (s, s+64).
// ---------------------------------------------------------------------------
__global__ __launch_bounds__(256) void gemm_mfma_kernel(
    const float* __restrict__ X, const ushort* __restrict__ Wf,
    const ushort* __restrict__ Wfs,
    uint* __restrict__ Hb32, float* __restrict__ s_src, float* __restrict__ s_dst,
    int M) {
  __shared__ __align__(16) char Xs[4][8192];   // per-wave 16 rows x 256 bf16
  const int tid = threadIdx.x;
  const int l = tid & 63;
  const int w = tid >> 6;
  const int lc = l & 15;
  const int lg = l >> 4;
  const int rowW = blockIdx.x * TM + w * 16;   // this wave's 16-row window
  char* myXs = Xs[w];

  // --- per-wave coalesced staging ---
  const int h = l >> 5, kbs = l & 31;
#pragma unroll
  for (int i = 0; i < 8; ++i) {
    int rr = 2 * i + h;
    int gr = rowW + rr; gr = (gr < M) ? gr : (M - 1);   // clamp: OOB rows never stored
    const f32x4* p = (const f32x4*)(X + (size_t)gr * F_IN + kbs * 8);
    f32x4 v0 = p[0], v1 = p[1];
    union { s16x8 vv; ushort uu[8]; } t;
    t.uu[0] = f2bf(v0[0]); t.uu[1] = f2bf(v0[1]); t.uu[2] = f2bf(v0[2]); t.uu[3] = f2bf(v0[3]);
    t.uu[4] = f2bf(v1[0]); t.uu[5] = f2bf(v1[1]); t.uu[6] = f2bf(v1[2]); t.uu[7] = f2bf(v1[3]);
    int byte = kbs * 256 + (rr ^ (kbs & 7)) * 16;
    *(s16x8*)(myXs + byte) = t.vv;
  }

  // --- MFMA main loop (same-wave RAW on LDS; no barrier) ---
  f32x4 acc[8] = {};        // colfrag j = 0..7 (cols j*16 + lc)
  f32x4 accS[1] = {};       // wa frag (s_src col0, s_dst col1)
  f32x4 aS = {0.f, 0.f, 0.f, 0.f};
#pragma unroll
  for (int ks = 0; ks < 8; ++ks) {
    int kb = ks * 4 + lg;
    int ab = kb * 256 + (lc ^ (kb & 7)) * 16;
    s16x8 af = *(const s16x8*)(myXs + ab);
    s16x8 bS = *(const s16x8*)&Wfs[((size_t)kb * 16 + lc) * 8];
#pragma unroll
    for (int j = 0; j < 8; ++j) {
      s16x8 bj = *(const s16x8*)&Wf[((size_t)kb * F_OUT + j * 16 + lc) * 8];
      acc[j] = __builtin_amdgcn_mfma_f32_16x16x32_bf16(af, bj, acc[j], 0, 0, 0);
    }
    aS = __builtin_amdgcn_mfma_f32_16x16x32_bf16(af, bS, aS, 0, 0, 0);
  }

  // --- store: slot s = j*16+lc packs cols (s, s+64) ---
#pragma unroll
  for (int q = 0; q < 4; ++q) {
    int rg = rowW + lg * 4 + q;
    if (rg < M) {
#pragma unroll
      for (int j = 0; j < 4; ++j)
        Hb32[(size_t)rg * 64 + j * 16 + lc] = pk2bf(acc[j][q], acc[j + 4][q]);
    }
  }

  // s_src (lc==0) / s_dst (lc==1) straight from aS
  if (lc < 2) {
    float* sout = (lc == 0) ? s_src : s_dst;
#pragma unroll
    for (int q = 0; q < 4; ++q) {
      int rg = rowW + lg * 4 + q;
      if (rg < M) sout[rg] = aS[q];
    }
  }
}

// ---------------------------------------------------------------------------
// Hist standalone (low VGPR, full occupancy for atomic latency hiding):
// deg histogram AND per-edge rank (the atomicAdd return), 4 edges/thread.
// ---------------------------------------------------------------------------
__global__ __launch_bounds__(256) void hist_rank_kernel(
    const int* __restrict__ src, int* __restrict__ deg,
    int* __restrict__ rank, int E) {
  int e0 = (blockIdx.x * 256 + threadIdx.x) * 4;
  if (e0 + 4 <= E) {
    int4 s4 = *(const int4*)(src + e0);
    int4 r4;
    r4.x = atomicAdd(&deg[s4.x], 1);
    r4.y = atomicAdd(&deg[s4.y], 1);
    r4.z = atomicAdd(&deg[s4.z], 1);
    r4.w = atomicAdd(&deg[s4.w], 1);
    *(int4*)(rank + e0) = r4;
  } else {
    for (int e = e0; e < E; ++e) rank[e] = atomicAdd(&deg[src[e]], 1);
  }
}

// ---------------------------------------------------------------------------
// Per-256-chunk sums of deg (input to the fused scan).
// ---------------------------------------------------------------------------
__global__ void block_sums_kernel(const int* __restrict__ deg, int* __restrict__ bs, int N) {
  int i = blockIdx.x * 256 + threadIdx.x;
  int v = (i < N) ? deg[i] : 0;
  int lane = threadIdx.x & 63, w = threadIdx.x >> 6;
#pragma unroll
  for (int d = 32; d >= 1; d >>= 1) v += __shfl_down(v, d);
  __shared__ int wsum[4];
  if (lane == 0) wsum[w] = v;
  __syncthreads();
  if (threadIdx.x == 0) bs[blockIdx.x] = wsum[0] + wsum[1] + wsum[2] + wsum[3];
}

// ---------------------------------------------------------------------------
// Fused scan: every block redundantly exclusive-scans bs[0..NS) (NS<=256)
// to get its offset, then scans its 256 deg values.
// ---------------------------------------------------------------------------
__global__ void scan_deg_kernel(const int* __restrict__ deg, const int* __restrict__ bs,
                                int* __restrict__ rowptr, int N, int E, int NS) {
  __shared__ int sc[256];
  __shared__ int wsumA[4], wsumB[4];
  int tid = threadIdx.x;
  int lane = tid & 63, w = tid >> 6;

  int bv = (tid < NS) ? bs[tid] : 0;
  int ibv = bv;
#pragma unroll
  for (int d = 1; d < 64; d <<= 1) {
    int t = __shfl_up(ibv, d);
    if (lane >= d) ibv += t;
  }
  if (lane == 63) wsumA[w] = ibv;
  __syncthreads();
  int boff = 0;
  for (int x = 0; x < w; ++x) boff += wsumA[x];
  sc[tid] = boff + ibv - bv;          // exclusive prefix of bs

  int i = blockIdx.x * 256 + tid;
  int v = (i < N) ? deg[i] : 0;
  int iv = v;
#pragma unroll
  for (int d = 1; d < 64; d <<= 1) {
    int t = __shfl_up(iv, d);
    if (lane >= d) iv += t;
  }
  if (lane == 63) wsumB[w] = iv;
  __syncthreads();                    // covers sc and wsumB
  int off = sc[blockIdx.x];
  for (int x = 0; x < w; ++x) off += wsumB[x];
  int excl = off + iv - v;
  if (i < N) rowptr[i] = excl;
  if (i == N - 1) rowptr[N] = E;
}

// ---------------------------------------------------------------------------
// Atomic-free scatter: colidx[rowptr[s] + rank[e]] = dst[e].
// ---------------------------------------------------------------------------
__global__ __launch_bounds__(256) void scatter_kernel(
    const int* __restrict__ src, const int* __restrict__ dst,
    const int* __restrict__ rank, const int* __restrict__ rowptr,
    int* __restrict__ colidx, int E) {
  int e0 = (blockIdx.x * 256 + threadIdx.x) * 4;
  if (e0 + 4 <= E) {
    int4 s4 = *(const int4*)(src + e0);
    int4 d4 = *(const int4*)(dst + e0);
    int4 r4 = *(const int4*)(rank + e0);
    colidx[rowptr[s4.x] + r4.x] = d4.x;
    colidx[rowptr[s4.y] + r4.y] = d4.y;
    colidx[rowptr[s4.z] + r4.z] = d4.z;
    colidx[rowptr[s4.w] + r4.w] = d4.w;
  } else {
    for (int e = e0; e < E; ++e) colidx[rowptr[src[e]] + rank[e]] = dst[e];
  }
}

// ---------------------------------------------------------------------------
// Aggregation: one wave per node (4/block). Lane-parallel softmax per
// <=64-edge chunk, then 4-edge-parallel gather: wave = 4 groups x 16 lanes,
// group g takes edge k+g, lane lc loads uint4 (16B). 8 edges/iter.
// Final shfl_xor(16,32) group-reduce. Slot s packs cols (s, s+64).
// ---------------------------------------------------------------------------
__global__ __launch_bounds__(256) void aggregate_kernel(
    const uint* __restrict__ H32, const float* __restrict__ s_src,
    const float* __restrict__ s_dst, const int* __restrict__ rowptr,
    const int* __restrict__ colidx, float* __restrict__ out, int M) {
  int node = blockIdx.x * 4 + (threadIdx.x >> 6);
  int l = threadIdx.x & 63;
  if (node >= M) return;
  const int g = l >> 4;       // edge group 0..3
  const int lc = l & 15;      // column lane within group
  int beg = rowptr[node], end = rowptr[node + 1];
  float ssrc = s_src[node];
  float m = -INFINITY, denom = 0.f;
  float acc[8] = {};

  for (int base = beg; base < end; base += 64) {
    int cnt = end - base; if (cnt > 64) cnt = 64;
    int jv = 0; float ev = -INFINITY;
    if (l < cnt) {
      jv = colidx[base + l];
      float e = ssrc + s_dst[jv];
      ev = (e > 0.f) ? e : ALPHA * e;
    }
    float cm = ev;
#pragma unroll
    for (int mask = 1; mask < 64; mask <<= 1) cm = fmaxf(cm, __shfl_xor(cm, mask));
    float mn = fmaxf(m, cm);
    float wv = (l < cnt) ? __expf(ev - mn) : 0.f;
    float sw = wv;
#pragma unroll
    for (int mask = 1; mask < 64; mask <<= 1) sw += __shfl_xor(sw, mask);
    float resc = __expf(m - mn);   // first chunk: exp(-inf) = 0
    denom = denom * resc + sw;
#pragma unroll
    for (int t = 0; t < 8; ++t) acc[t] *= resc;
    m = mn;

    for (int k = 0; k < cnt; k += 8) {
      int k0 = k + g, k1 = k + 4 + g;
      int j0 = __shfl(jv, k0);
      int j1 = (k1 < 64) ? __shfl(jv, k1) : 0;
      float w0 = __shfl(wv, k0);
      float w1 = (k1 < 64) ? __shfl(wv, k1) : 0.f;
      uint4 u0 = *(const uint4*)(H32 + ((size_t)(uint)j0 << 6) + lc * 4);
      uint4 u1 = *(const uint4*)(H32 + ((size_t)(uint)j1 << 6) + lc * 4);
      acc[0] += w0 * bflo(u0.x) + w1 * bflo(u1.x);
      acc[1] += w0 * bfhi(u0.x) + w1 * bfhi(u1.x);
      acc[2] += w0 * bflo(u0.y) + w1 * bflo(u1.y);
      acc[3] += w0 * bfhi(u0.y) + w1 * bfhi(u1.y);
      acc[4] += w0 * bflo(u0.z) + w1 * bflo(u1.z);
      acc[5] += w0 * bfhi(u0.z) + w1 * bfhi(u1.z);
      acc[6] += w0 * bflo(u0.w) + w1 * bflo(u1.w);
      acc[7] += w0 * bfhi(u0.w) + w1 * bfhi(u1.w);
    }
  }

#pragma unroll
  for (int t = 0; t < 8; ++t) {
    acc[t] += __shfl_xor(acc[t], 16);
    acc[t] += __shfl_xor(acc[t], 32);
  }
  float inv = (denom > 0.f) ? 1.f / denom : 0.f;
  if (g == 0) {
    float4 v;
    v.x = acc[0] * inv; v.y = acc[2] * inv; v.z = acc[4] * inv; v.w = acc[6] * inv;
    v.x = (v.x > 0.f) ? v.x : __expf(v.x) - 1.f;
    v.y = (v.y > 0.f) ? v.y : __expf(v.y) - 1.f;
    v.z = (v.z > 0.f) ? v.z : __expf(v.z) - 1.f;
    v.w = (v.w > 0.f) ? v.w : __expf(v.w) - 1.f;
    *(float4*)&out[(size_t)node * 128 + lc * 4] = v;
  } else if (g == 1) {
    float4 v;
    v.x = acc[1] * inv; v.y = acc[3] * inv; v.z = acc[5] * inv; v.w = acc[7] * inv;
    v.x = (v.x > 0.f) ? v.x : __expf(v.x) - 1.f;
    v.y = (v.y > 0.f) ? v.y : __expf(v.y) - 1.f;
    v.z = (v.z > 0.f) ? v.z : __expf(v.z) - 1.f;
    v.w = (v.w > 0.f) ? v.w : __expf(v.w) - 1.f;
    *(float4*)&out[(size_t)node * 128 + 64 + lc * 4] = v;
  }
}

// ---------------------------------------------------------------------------
extern "C" void kernel_launch(void* const* d_in, const int* in_sizes, int n_in,
                              void* d_out, int out_size, void* d_ws, size_t ws_size,
                              hipStream_t stream) {
  const float* x    = (const float*)d_in[0];
  const float* W    = (const float*)d_in[1];
  const float* avec = (const float*)d_in[2];
  const int*   edge = (const int*)d_in[3];

  const int M = in_sizes[0] / F_IN;   // 50000
  const int E = in_sizes[3] / 2;      // 800000
  const int* src = edge;
  const int* dst = edge + E;
  float* out = (float*)d_out;

  char* ws = (char*)d_ws;
  uint*   Hb32  = (uint*)ws;   ws += (size_t)M * 64 * sizeof(uint);
  ushort* Wf    = (ushort*)ws; ws += (size_t)32 * F_OUT * 8 * sizeof(ushort);
  ushort* Wfs   = (ushort*)ws; ws += (size_t)32 * 16 * 8 * sizeof(ushort);
  float* s_src  = (float*)ws;  ws += (size_t)M * sizeof(float);
  float* s_dst  = (float*)ws;  ws += (size_t)M * sizeof(float);
  int*   deg    = (int*)ws;    ws += (size_t)M * sizeof(int);
  int*   rowptr = (int*)ws;    ws += (size_t)(M + 1) * sizeof(int);
  int*   rank   = (int*)ws;    ws += (size_t)E * sizeof(int);
  int*   colidx = (int*)ws;    ws += (size_t)E * sizeof(int);
  int*   bsums  = (int*)ws;

  const int NS = (M + 255) / 256;                      // 196 (<= 256 required)
  const int n4 = M / 4;                                // deg zero (M % 4 == 0)
  const int ZB = (n4 + 255) / 256;                     // zero blocks
  const int E4 = (E + 1023) / 1024;                    // 4-edge/thread blocks
  const int G  = (M + TM - 1) / TM;                    // gemm blocks

  prep_kernel<<<ZB + 17, 256, 0, stream>>>(W, avec, Wf, Wfs, (int4*)deg, n4, ZB);
  hist_rank_kernel<<<E4, 256, 0, stream>>>(src, deg, rank, E);
  gemm_mfma_kernel<<<G, 256, 0, stream>>>(x, Wf, Wfs, Hb32, s_src, s_dst, M);
  block_sums_kernel<<<NS, 256, 0, stream>>>(deg, bsums, M);
  scan_deg_kernel<<<NS, 256, 0, stream>>>(deg, bsums, rowptr, M, E, NS);
  scatter_kernel<<<E4, 256, 0, stream>>>(src, dst, rank, rowptr, colidx, E);
  aggregate_kernel<<<(M + 3) / 4, 256, 0, stream>>>(Hb32, s_src, s_dst, rowptr, colidx, out, M);
}

// Round 15
// 108.250 us; speedup vs baseline: 1.2379x; 1.0886x over previous
//
#include <hip/hip_runtime.h>
#include <hip/hip_bf16.h>
#include <math.h>

#define F_IN   256
#define F_OUT  128
#define ALPHA  0.2f
#define TM     64       // GEMM row tile (4 waves x 16 rows)

typedef __attribute__((ext_vector_type(8))) short s16x8;
typedef __attribute__((ext_vector_type(4))) float f32x4;

__device__ __forceinline__ ushort f2bf(float f) {
  __hip_bfloat16 h = __float2bfloat16(f);
  return *reinterpret_cast<ushort*>(&h);
}
__device__ __forceinline__ uint pk2bf(float lo, float hi) {
  return (uint)f2bf(lo) | ((uint)f2bf(hi) << 16);
}
__device__ __forceinline__ float bflo(uint u) { return __uint_as_float(u << 16); }
__device__ __forceinline__ float bfhi(uint u) { return __uint_as_float(u & 0xffff0000u); }

// ---------------------------------------------------------------------------
// Prep: blocks [0,ZB): zero deg (int4); [ZB,ZB+16): pack Wf; ZB+16: pack Wfs.
// ---------------------------------------------------------------------------
__global__ __launch_bounds__(256) void prep_kernel(
    const float* __restrict__ W, const float* __restrict__ avec,
    ushort* __restrict__ Wf, ushort* __restrict__ Wfs,
    int4* __restrict__ deg4, int n4, int ZB) {
  int b = blockIdx.x;
  if (b < ZB) {
    int i = b * 256 + threadIdx.x;
    if (i < n4) deg4[i] = make_int4(0, 0, 0, 0);
  } else if (b < ZB + 16) {
    int idx = (b - ZB) * 256 + threadIdx.x;   // 4096 fragments-of-8
    int kb = idx >> 7, c = idx & 127;
    union { s16x8 v; ushort u[8]; } t;
#pragma unroll
    for (int j = 0; j < 8; ++j) t.u[j] = f2bf(W[(kb * 8 + j) * F_OUT + c]);
    *(s16x8*)&Wf[(size_t)idx * 8] = t.v;
  } else {
    int k = threadIdx.x;   // 0..255 = K row of W
    float s1 = 0.f, s2 = 0.f;
    for (int c = 0; c < F_OUT; ++c) {
      float wv = W[k * F_OUT + c];
      s1 += wv * avec[c];
      s2 += wv * avec[F_OUT + c];
    }
    int kb = k >> 3, j8 = k & 7;
    ushort b1 = f2bf(s1), b2 = f2bf(s2);
#pragma unroll
    for (int cc = 0; cc < 16; ++cc) {
      ushort v = (cc == 0) ? b1 : (cc == 1) ? b2 : (ushort)0;
      Wfs[((size_t)kb * 16 + cc) * 8 + j8] = v;
    }
  }
}

// ---------------------------------------------------------------------------
// Fused wave-autonomous GEMM + hist (grid-partitioned, independent data):
// blocks [0,G): GEMM; blocks [G,..): 4-edge/thread histogram + rank.
// Fusion is free for hist here: this kernel's 100VGPR/32KB-LDS footprint
// still allows ~16 waves/CU for hist blocks == hist's standalone occupancy,
// and hist's scattered-atomic latency hides under GEMM memory phases (r12
// showed the overlap win; r14 showed the barrier-free GEMM win; this takes
// both).
//
// GEMM (NO __syncthreads): each wave owns 16 rows x 128 cols, stages its own
// rows into its own 8KB LDS quarter (producer==consumer => lgkmcnt ordering
// suffices). Global loads fully coalesced (lane 0-31 = one row's 1KB).
// Staging: iter i, lane l (h=l>>5, kbs=l&31) loads X[rowW+2i+h][kbs*8..+8]
// (32B), converts to bf16, writes 16B at kbs*256 + ((2i+h)^(kbs&7))*16
// [XOR swizzle both sides]. A-frag read per ks: kb=ks*4+lg, byte
// kb*256+((lc)^(kb&7))*16 -> conflict-free ds_read_b128. B-frags from L2-hot
// Wf. C/D: col=l&15, row=(l>>4)*4+q. Hb32 slot s=j*16+lc packs cols (s,s+64).
// ---------------------------------------------------------------------------
__global__ __launch_bounds__(256) void gemm_hist_kernel(
    const float* __restrict__ X, const ushort* __restrict__ Wf,
    const ushort* __restrict__ Wfs,
    uint* __restrict__ Hb32, float* __restrict__ s_src, float* __restrict__ s_dst,
    int M, int G,
    const int* __restrict__ src, int* __restrict__ deg,
    int* __restrict__ rank, int E) {
  __shared__ __align__(16) char Xs[4][8192];   // per-wave 16 rows x 256 bf16
  const int tid = threadIdx.x;

  if (blockIdx.x >= G) {
    // ---- hist partition: deg histogram + per-edge rank ----
    int e0 = ((blockIdx.x - G) * 256 + tid) * 4;
    if (e0 + 4 <= E) {
      int4 s4 = *(const int4*)(src + e0);
      int4 r4;
      r4.x = atomicAdd(&deg[s4.x], 1);
      r4.y = atomicAdd(&deg[s4.y], 1);
      r4.z = atomicAdd(&deg[s4.z], 1);
      r4.w = atomicAdd(&deg[s4.w], 1);
      *(int4*)(rank + e0) = r4;
    } else {
      for (int e = e0; e < E; ++e) rank[e] = atomicAdd(&deg[src[e]], 1);
    }
    return;
  }

  // ---- GEMM partition ----
  const int l = tid & 63;
  const int w = tid >> 6;
  const int lc = l & 15;
  const int lg = l >> 4;
  const int rowW = blockIdx.x * TM + w * 16;   // this wave's 16-row window
  char* myXs = Xs[w];

  // per-wave coalesced staging
  const int h = l >> 5, kbs = l & 31;
#pragma unroll
  for (int i = 0; i < 8; ++i) {
    int rr = 2 * i + h;
    int gr = rowW + rr; gr = (gr < M) ? gr : (M - 1);   // clamp: OOB rows never stored
    const f32x4* p = (const f32x4*)(X + (size_t)gr * F_IN + kbs * 8);
    f32x4 v0 = p[0], v1 = p[1];
    union { s16x8 vv; ushort uu[8]; } t;
    t.uu[0] = f2bf(v0[0]); t.uu[1] = f2bf(v0[1]); t.uu[2] = f2bf(v0[2]); t.uu[3] = f2bf(v0[3]);
    t.uu[4] = f2bf(v1[0]); t.uu[5] = f2bf(v1[1]); t.uu[6] = f2bf(v1[2]); t.uu[7] = f2bf(v1[3]);
    int byte = kbs * 256 + (rr ^ (kbs & 7)) * 16;
    *(s16x8*)(myXs + byte) = t.vv;
  }

  // MFMA main loop (same-wave RAW on LDS; no barrier)
  f32x4 acc[8] = {};        // colfrag j = 0..7 (cols j*16 + lc)
  f32x4 aS = {0.f, 0.f, 0.f, 0.f};
#pragma unroll
  for (int ks = 0; ks < 8; ++ks) {
    int kb = ks * 4 + lg;
    int ab = kb * 256 + (lc ^ (kb & 7)) * 16;
    s16x8 af = *(const s16x8*)(myXs + ab);
    s16x8 bS = *(const s16x8*)&Wfs[((size_t)kb * 16 + lc) * 8];
#pragma unroll
    for (int j = 0; j < 8; ++j) {
      s16x8 bj = *(const s16x8*)&Wf[((size_t)kb * F_OUT + j * 16 + lc) * 8];
      acc[j] = __builtin_amdgcn_mfma_f32_16x16x32_bf16(af, bj, acc[j], 0, 0, 0);
    }
    aS = __builtin_amdgcn_mfma_f32_16x16x32_bf16(af, bS, aS, 0, 0, 0);
  }

  // store: slot s = j*16+lc packs cols (s, s+64)
#pragma unroll
  for (int q = 0; q < 4; ++q) {
    int rg = rowW + lg * 4 + q;
    if (rg < M) {
#pragma unroll
      for (int j = 0; j < 4; ++j)
        Hb32[(size_t)rg * 64 + j * 16 + lc] = pk2bf(acc[j][q], acc[j + 4][q]);
    }
  }

  // s_src (lc==0) / s_dst (lc==1) straight from aS
  if (lc < 2) {
    float* sout = (lc == 0) ? s_src : s_dst;
#pragma unroll
    for (int q = 0; q < 4; ++q) {
      int rg = rowW + lg * 4 + q;
      if (rg < M) sout[rg] = aS[q];
    }
  }
}

// ---------------------------------------------------------------------------
// Per-256-chunk sums of deg (input to the fused scan).
// ---------------------------------------------------------------------------
__global__ void block_sums_kernel(const int* __restrict__ deg, int* __restrict__ bs, int N) {
  int i = blockIdx.x * 256 + threadIdx.x;
  int v = (i < N) ? deg[i] : 0;
  int lane = threadIdx.x & 63, w = threadIdx.x >> 6;
#pragma unroll
  for (int d = 32; d >= 1; d >>= 1) v += __shfl_down(v, d);
  __shared__ int wsum[4];
  if (lane == 0) wsum[w] = v;
  __syncthreads();
  if (threadIdx.x == 0) bs[blockIdx.x] = wsum[0] + wsum[1] + wsum[2] + wsum[3];
}

// ---------------------------------------------------------------------------
// Fused scan: every block redundantly exclusive-scans bs[0..NS) (NS<=256)
// to get its offset, then scans its 256 deg values.
// ---------------------------------------------------------------------------
__global__ void scan_deg_kernel(const int* __restrict__ deg, const int* __restrict__ bs,
                                int* __restrict__ rowptr, int N, int E, int NS) {
  __shared__ int sc[256];
  __shared__ int wsumA[4], wsumB[4];
  int tid = threadIdx.x;
  int lane = tid & 63, w = tid >> 6;

  int bv = (tid < NS) ? bs[tid] : 0;
  int ibv = bv;
#pragma unroll
  for (int d = 1; d < 64; d <<= 1) {
    int t = __shfl_up(ibv, d);
    if (lane >= d) ibv += t;
  }
  if (lane == 63) wsumA[w] = ibv;
  __syncthreads();
  int boff = 0;
  for (int x = 0; x < w; ++x) boff += wsumA[x];
  sc[tid] = boff + ibv - bv;          // exclusive prefix of bs

  int i = blockIdx.x * 256 + tid;
  int v = (i < N) ? deg[i] : 0;
  int iv = v;
#pragma unroll
  for (int d = 1; d < 64; d <<= 1) {
    int t = __shfl_up(iv, d);
    if (lane >= d) iv += t;
  }
  if (lane == 63) wsumB[w] = iv;
  __syncthreads();                    // covers sc and wsumB
  int off = sc[blockIdx.x];
  for (int x = 0; x < w; ++x) off += wsumB[x];
  int excl = off + iv - v;
  if (i < N) rowptr[i] = excl;
  if (i == N - 1) rowptr[N] = E;
}

// ---------------------------------------------------------------------------
// Atomic-free scatter: colidx[rowptr[s] + rank[e]] = dst[e].
// ---------------------------------------------------------------------------
__global__ __launch_bounds__(256) void scatter_kernel(
    const int* __restrict__ src, const int* __restrict__ dst,
    const int* __restrict__ rank, const int* __restrict__ rowptr,
    int* __restrict__ colidx, int E) {
  int e0 = (blockIdx.x * 256 + threadIdx.x) * 4;
  if (e0 + 4 <= E) {
    int4 s4 = *(const int4*)(src + e0);
    int4 d4 = *(const int4*)(dst + e0);
    int4 r4 = *(const int4*)(rank + e0);
    colidx[rowptr[s4.x] + r4.x] = d4.x;
    colidx[rowptr[s4.y] + r4.y] = d4.y;
    colidx[rowptr[s4.z] + r4.z] = d4.z;
    colidx[rowptr[s4.w] + r4.w] = d4.w;
  } else {
    for (int e = e0; e < E; ++e) colidx[rowptr[src[e]] + rank[e]] = dst[e];
  }
}

// ---------------------------------------------------------------------------
// Aggregation: one wave per node (4/block). Lane-parallel softmax per
// <=64-edge chunk, then 4-edge-parallel gather: wave = 4 groups x 16 lanes,
// group g takes edge k+g, lane lc loads uint4 (16B). 8 edges/iter.
// Final shfl_xor(16,32) group-reduce. Slot s packs cols (s, s+64).
// ---------------------------------------------------------------------------
__global__ __launch_bounds__(256) void aggregate_kernel(
    const uint* __restrict__ H32, const float* __restrict__ s_src,
    const float* __restrict__ s_dst, const int* __restrict__ rowptr,
    const int* __restrict__ colidx, float* __restrict__ out, int M) {
  int node = blockIdx.x * 4 + (threadIdx.x >> 6);
  int l = threadIdx.x & 63;
  if (node >= M) return;
  const int g = l >> 4;       // edge group 0..3
  const int lc = l & 15;      // column lane within group
  int beg = rowptr[node], end = rowptr[node + 1];
  float ssrc = s_src[node];
  float m = -INFINITY, denom = 0.f;
  float acc[8] = {};

  for (int base = beg; base < end; base += 64) {
    int cnt = end - base; if (cnt > 64) cnt = 64;
    int jv = 0; float ev = -INFINITY;
    if (l < cnt) {
      jv = colidx[base + l];
      float e = ssrc + s_dst[jv];
      ev = (e > 0.f) ? e : ALPHA * e;
    }
    float cm = ev;
#pragma unroll
    for (int mask = 1; mask < 64; mask <<= 1) cm = fmaxf(cm, __shfl_xor(cm, mask));
    float mn = fmaxf(m, cm);
    float wv = (l < cnt) ? __expf(ev - mn) : 0.f;
    float sw = wv;
#pragma unroll
    for (int mask = 1; mask < 64; mask <<= 1) sw += __shfl_xor(sw, mask);
    float resc = __expf(m - mn);   // first chunk: exp(-inf) = 0
    denom = denom * resc + sw;
#pragma unroll
    for (int t = 0; t < 8; ++t) acc[t] *= resc;
    m = mn;

    for (int k = 0; k < cnt; k += 8) {
      int k0 = k + g, k1 = k + 4 + g;
      int j0 = __shfl(jv, k0);
      int j1 = (k1 < 64) ? __shfl(jv, k1) : 0;
      float w0 = __shfl(wv, k0);
      float w1 = (k1 < 64) ? __shfl(wv, k1) : 0.f;
      uint4 u0 = *(const uint4*)(H32 + ((size_t)(uint)j0 << 6) + lc * 4);
      uint4 u1 = *(const uint4*)(H32 + ((size_t)(uint)j1 << 6) + lc * 4);
      acc[0] += w0 * bflo(u0.x) + w1 * bflo(u1.x);
      acc[1] += w0 * bfhi(u0.x) + w1 * bfhi(u1.x);
      acc[2] += w0 * bflo(u0.y) + w1 * bflo(u1.y);
      acc[3] += w0 * bfhi(u0.y) + w1 * bfhi(u1.y);
      acc[4] += w0 * bflo(u0.z) + w1 * bflo(u1.z);
      acc[5] += w0 * bfhi(u0.z) + w1 * bfhi(u1.z);
      acc[6] += w0 * bflo(u0.w) + w1 * bflo(u1.w);
      acc[7] += w0 * bfhi(u0.w) + w1 * bfhi(u1.w);
    }
  }

#pragma unroll
  for (int t = 0; t < 8; ++t) {
    acc[t] += __shfl_xor(acc[t], 16);
    acc[t] += __shfl_xor(acc[t], 32);
  }
  float inv = (denom > 0.f) ? 1.f / denom : 0.f;
  if (g == 0) {
    float4 v;
    v.x = acc[0] * inv; v.y = acc[2] * inv; v.z = acc[4] * inv; v.w = acc[6] * inv;
    v.x = (v.x > 0.f) ? v.x : __expf(v.x) - 1.f;
    v.y = (v.y > 0.f) ? v.y : __expf(v.y) - 1.f;
    v.z = (v.z > 0.f) ? v.z : __expf(v.z) - 1.f;
    v.w = (v.w > 0.f) ? v.w : __expf(v.w) - 1.f;
    *(float4*)&out[(size_t)node * 128 + lc * 4] = v;
  } else if (g == 1) {
    float4 v;
    v.x = acc[1] * inv; v.y = acc[3] * inv; v.z = acc[5] * inv; v.w = acc[7] * inv;
    v.x = (v.x > 0.f) ? v.x : __expf(v.x) - 1.f;
    v.y = (v.y > 0.f) ? v.y : __expf(v.y) - 1.f;
    v.z = (v.z > 0.f) ? v.z : __expf(v.z) - 1.f;
    v.w = (v.w > 0.f) ? v.w : __expf(v.w) - 1.f;
    *(float4*)&out[(size_t)node * 128 + 64 + lc * 4] = v;
  }
}

// ---------------------------------------------------------------------------
extern "C" void kernel_launch(void* const* d_in, const int* in_sizes, int n_in,
                              void* d_out, int out_size, void* d_ws, size_t ws_size,
                              hipStream_t stream) {
  const float* x    = (const float*)d_in[0];
  const float* W    = (const float*)d_in[1];
  const float* avec = (const float*)d_in[2];
  const int*   edge = (const int*)d_in[3];

  const int M = in_sizes[0] / F_IN;   // 50000
  const int E = in_sizes[3] / 2;      // 800000
  const int* src = edge;
  const int* dst = edge + E;
  float* out = (float*)d_out;

  char* ws = (char*)d_ws;
  uint*   Hb32  = (uint*)ws;   ws += (size_t)M * 64 * sizeof(uint);
  ushort* Wf    = (ushort*)ws; ws += (size_t)32 * F_OUT * 8 * sizeof(ushort);
  ushort* Wfs   = (ushort*)ws; ws += (size_t)32 * 16 * 8 * sizeof(ushort);
  float* s_src  = (float*)ws;  ws += (size_t)M * sizeof(float);
  float* s_dst  = (float*)ws;  ws += (size_t)M * sizeof(float);
  int*   deg    = (int*)ws;    ws += (size_t)M * sizeof(int);
  int*   rowptr = (int*)ws;    ws += (size_t)(M + 1) * sizeof(int);
  int*   rank   = (int*)ws;    ws += (size_t)E * sizeof(int);
  int*   colidx = (int*)ws;    ws += (size_t)E * sizeof(int);
  int*   bsums  = (int*)ws;

  const int NS = (M + 255) / 256;                      // 196 (<= 256 required)
  const int n4 = M / 4;                                // deg zero (M % 4 == 0)
  const int ZB = (n4 + 255) / 256;                     // zero blocks
  const int E4 = (E + 1023) / 1024;                    // 4-edge/thread blocks
  const int G  = (M + TM - 1) / TM;                    // gemm blocks

  prep_kernel<<<ZB + 17, 256, 0, stream>>>(W, avec, Wf, Wfs, (int4*)deg, n4, ZB);
  gemm_hist_kernel<<<G + E4, 256, 0, stream>>>(x, Wf, Wfs, Hb32, s_src, s_dst,
                                               M, G, src, deg, rank, E);
  block_sums_kernel<<<NS, 256, 0, stream>>>(deg, bsums, M);
  scan_deg_kernel<<<NS, 256, 0, stream>>>(deg, bsums, rowptr, M, E, NS);
  scatter_kernel<<<E4, 256, 0, stream>>>(src, dst, rank, rowptr, colidx, E);
  aggregate_kernel<<<(M + 3) / 4, 256, 0, stream>>>(Hb32, s_src, s_dst, rowptr, colidx, out, M);
}